// Round 5
// baseline (569.886 us; speedup 1.0000x reference)
//
#include <hip/hip_runtime.h>

// Fused gated aggregator, split into two streaming kernels:
//   K1 agg_v:    V = (nodes@Wt+bt)*sigmoid(nodes@Wg+bg) -> bf16 tiles in ws
//                tile layout: [chunk c][128 d][32 node] (8 KB contiguous)
//   K2 agg_pool: out[B,D] = owner_masks @ V  (mask bits in LDS, no barriers)
//   K3 agg_reduce: sum per-block partials.

#define NTOT   500000
#define NCHUNK 15625   // NTOT / 32, exact
#define NBLK1  1024    // K1 grid
#define NBLK2  512     // K2 grid

typedef unsigned long long u64;
typedef unsigned int u32;

typedef __attribute__((ext_vector_type(8))) unsigned short ushort8;
typedef __bf16 bf16x8 __attribute__((ext_vector_type(8)));
typedef __attribute__((ext_vector_type(4))) float f32x4;

static __device__ __forceinline__ u32 f2bf1(float f) {
  u32 u = __float_as_uint(f);
  u += 0x7fffu + ((u >> 16) & 1u);  // RNE
  return u >> 16;
}
static __device__ __forceinline__ u32 f2bf2(float a, float b) {
  return f2bf1(a) | (f2bf1(b) << 16);
}
// 2 bits -> packed pair of bf16 {0,1}
static __device__ __forceinline__ u32 bits2bf2(u32 byte, int j) {
  return ((byte >> j) & 1u ? 0x3F80u : 0u) | ((byte >> (j + 1)) & 1u ? 0x3F800000u : 0u);
}

// ======================= K1: V producer =======================
__global__ __launch_bounds__(512, 4)
void agg_v(const float* __restrict__ nodes,
           const float* __restrict__ Wt, const float* __restrict__ bt,
           const float* __restrict__ Wg, const float* __restrict__ bg,
           unsigned short* __restrict__ vt) {
  __shared__ __align__(16) unsigned short nodes_s[2][32][136];  // 17 KB dbuf

  const int tid = threadIdx.x;
  const int lane = tid & 63;
  const int w = tid >> 6;    // 0..7
  const int q = lane >> 4;
  const int r = lane & 15;

  const int bid = blockIdx.x;
  const int c0 = (int)(((long long)bid * NCHUNK) >> 10);
  const int c1 = (int)(((long long)(bid + 1) * NCHUNK) >> 10);
  const int nch = c1 - c0;   // 15 or 16
  const int n0 = c0 * 32;

  // W as B-operand fragments; wave w owns d in [16w, 16w+16)
  bf16x8 Wf[2][4];
  float btr, bgr;
  {
    const int d = w * 16 + r;
    btr = bt[d];
    bgr = bg[d];
#pragma unroll
    for (int ks = 0; ks < 4; ++ks) {
      u32 wv[4], gv[4];
#pragma unroll
      for (int j = 0; j < 4; ++j) {
        const int k = ks * 32 + q * 8 + 2 * j;
        wv[j] = f2bf2(Wt[k * 128 + d], Wt[(k + 1) * 128 + d]);
        gv[j] = f2bf2(Wg[k * 128 + d], Wg[(k + 1) * 128 + d]);
      }
      Wf[0][ks] = __builtin_bit_cast(bf16x8, *(ushort8*)wv);
      Wf[1][ks] = __builtin_bit_cast(bf16x8, *(ushort8*)gv);
    }
  }

  float4 nf[2];
  auto issue = [&](int cloc) {
    const int k0 = n0 + cloc * 32;
#pragma unroll
    for (int it = 0; it < 2; ++it) {
      const int flat = it * 512 + tid;
      const int nrow = flat >> 5, nc4 = flat & 31;
      nf[it] = *(const float4*)(nodes + (size_t)(k0 + nrow) * 128 + nc4 * 4);
    }
  };
  auto stage = [&](int buf) {
#pragma unroll
    for (int it = 0; it < 2; ++it) {
      const int flat = it * 512 + tid;
      const int nrow = flat >> 5, nc4 = flat & 31;
      const u32 lo = f2bf2(nf[it].x, nf[it].y);
      const u32 hi = f2bf2(nf[it].z, nf[it].w);
      *(u64*)&nodes_s[buf][nrow][nc4 * 4] = (u64)lo | ((u64)hi << 32);
    }
  };

  issue(0);
  stage(0);

  const f32x4 fzero = {0.f, 0.f, 0.f, 0.f};
  const int d = w * 16 + r;

  for (int c = 0; c < nch; ++c) {
    __syncthreads();               // buf[c&1] staged (end of prev iter)
    if (c + 1 < nch) issue(c + 1); // in flight across this chunk's compute
    const int buf = c & 1;

    f32x4 aD[2], aG[2];
    aD[0] = fzero; aD[1] = fzero; aG[0] = fzero; aG[1] = fzero;
#pragma unroll
    for (int ks = 0; ks < 4; ++ks) {
      bf16x8 a0 = *(const bf16x8*)&nodes_s[buf][r][ks * 32 + q * 8];
      bf16x8 a1 = *(const bf16x8*)&nodes_s[buf][16 + r][ks * 32 + q * 8];
      aD[0] = __builtin_amdgcn_mfma_f32_16x16x32_bf16(a0, Wf[0][ks], aD[0], 0, 0, 0);
      aD[1] = __builtin_amdgcn_mfma_f32_16x16x32_bf16(a1, Wf[0][ks], aD[1], 0, 0, 0);
      aG[0] = __builtin_amdgcn_mfma_f32_16x16x32_bf16(a0, Wf[1][ks], aG[0], 0, 0, 0);
      aG[1] = __builtin_amdgcn_mfma_f32_16x16x32_bf16(a1, Wf[1][ks], aG[1], 0, 0, 0);
    }

    // epilogue -> V tile (global): tile[c0+c][d][node], node = mt*16+q*4+reg
    unsigned short* base = vt + (size_t)(c0 + c) * 4096 + d * 32;
#pragma unroll
    for (int mt = 0; mt < 2; ++mt) {
      float v[4];
#pragma unroll
      for (int reg = 0; reg < 4; ++reg) {
        const float x = aD[mt][reg] + btr;
        const float g = aG[mt][reg] + bgr;
        v[reg] = x * __builtin_amdgcn_rcpf(1.f + __expf(-g));
      }
      const u32 lo = f2bf2(v[0], v[1]);
      const u32 hi = f2bf2(v[2], v[3]);
      *(u64*)(base + mt * 16 + q * 4) = (u64)lo | ((u64)hi << 32);
    }

    if (c + 1 < nch) stage((c + 1) & 1);  // waits vmcnt here, not at barrier
  }
}

// ======================= K2: pooling =======================
template <bool ATOMIC>
__global__ __launch_bounds__(512, 4)
void agg_pool(const int* __restrict__ masks, const unsigned short* __restrict__ vt,
              float* __restrict__ outp) {
  __shared__ __align__(16) u64 bits[128][17];  // 17 KB (34-dword rows)

  const int tid = threadIdx.x;
  const int lane = tid & 63;
  const int w = tid >> 6;    // 0..7
  const int q = lane >> 4;
  const int r = lane & 15;

  const int bid = blockIdx.x;
  const int c0 = (int)(((long long)bid * NCHUNK) >> 9);
  const int c1 = (int)(((long long)(bid + 1) * NCHUNK) >> 9);
  const int nch = c1 - c0;   // 30 or 31
  const int n0 = c0 * 32;

  // ---- stage mask bits: wave w packs rows [16w, 16w+16) ----
  {
    const int row0 = w * 16;
    int cb = 16 * lane;
    if (cb >= nch * 32) cb = 0;  // clamp: never read
    int4 cur[4], nxt[4];
    auto ldrow = [&](int rr, int4* dst) {
      const int* p = masks + (size_t)(row0 + rr) * NTOT + n0 + cb;
#pragma unroll
      for (int i = 0; i < 4; ++i) dst[i] = *(const int4*)(p + 4 * i);
    };
    ldrow(0, cur);
#pragma unroll 4
    for (int rr = 0; rr < 16; ++rr) {
      if (rr < 15) ldrow(rr + 1, nxt);
      const int* m = (const int*)cur;
      u32 b = 0;
#pragma unroll
      for (int e = 0; e < 16; ++e) b |= (u32)(m[e] != 0) << e;
      ((unsigned short*)bits)[(row0 + rr) * 68 + lane] = (unsigned short)b;
#pragma unroll
      for (int i = 0; i < 4; ++i) cur[i] = nxt[i];
    }
  }
  __syncthreads();  // the only barrier

  // wave tile: 64 b x 32 d
  const int wd = w >> 1, wb = w & 1;
  const int d0 = wd * 32, b0 = wb * 64;

  const f32x4 fzero = {0.f, 0.f, 0.f, 0.f};
  f32x4 acc[4][2];
#pragma unroll
  for (int i = 0; i < 4; ++i) { acc[i][0] = fzero; acc[i][1] = fzero; }

  const u32* bitw = (const u32*)bits;  // row stride 34 dwords

  bf16x8 vb[2], vbn[2];
  auto loadv = [&](int cloc, bf16x8* dst) {
    const unsigned short* base = vt + (size_t)(c0 + cloc) * 4096 + q * 8;
#pragma unroll
    for (int nt = 0; nt < 2; ++nt)
      dst[nt] = *(const bf16x8*)(base + (d0 + nt * 16 + r) * 32);
  };

  loadv(0, vb);
  for (int c = 0; c < nch; ++c) {
    if (c + 1 < nch) loadv(c + 1, vbn);
#pragma unroll
    for (int mt = 0; mt < 4; ++mt) {
      const u32 dw = bitw[(b0 + mt * 16 + r) * 34 + c];
      const u32 byte = (dw >> (q * 8)) & 0xffu;
      u32 p[4];
      p[0] = bits2bf2(byte, 0);
      p[1] = bits2bf2(byte, 2);
      p[2] = bits2bf2(byte, 4);
      p[3] = bits2bf2(byte, 6);
      bf16x8 a = __builtin_bit_cast(bf16x8, *(ushort8*)p);
      acc[mt][0] = __builtin_amdgcn_mfma_f32_16x16x32_bf16(a, vb[0], acc[mt][0], 0, 0, 0);
      acc[mt][1] = __builtin_amdgcn_mfma_f32_16x16x32_bf16(a, vb[1], acc[mt][1], 0, 0, 0);
    }
    vb[0] = vbn[0];
    vb[1] = vbn[1];
  }

#pragma unroll
  for (int mt = 0; mt < 4; ++mt)
#pragma unroll
    for (int nt = 0; nt < 2; ++nt)
#pragma unroll
      for (int reg = 0; reg < 4; ++reg) {
        const int b = b0 + mt * 16 + q * 4 + reg;
        const int d = d0 + nt * 16 + r;
        if (ATOMIC)
          atomicAdd(&outp[b * 128 + d], acc[mt][nt][reg]);
        else
          outp[(size_t)bid * 16384 + b * 128 + d] = acc[mt][nt][reg];
      }
}

// ======================= K3: partial reduce =======================
__global__ __launch_bounds__(256)
void agg_reduce(const float* __restrict__ part, float* __restrict__ out) {
  // 512 blocks x 256 thr = 8 groups x 16384 outputs; 64 partials each
  const int gid = blockIdx.x * 256 + threadIdx.x;
  const int i = gid & 16383;
  const int grp = gid >> 14;
  const float* p = part + (size_t)grp * 64 * 16384 + i;
  float s = 0.f;
#pragma unroll 8
  for (int g = 0; g < 64; ++g) s += p[(size_t)g * 16384];
  atomicAdd(&out[i], s);
}

// ============= fallback: fused atomic (round-4 kernel) =============
__global__ __launch_bounds__(512, 4)
void agg_fused(const float* __restrict__ nodes, const int* __restrict__ masks,
               const float* __restrict__ Wt, const float* __restrict__ bt,
               const float* __restrict__ Wg, const float* __restrict__ bg,
               float* __restrict__ outp) {
  __shared__ __align__(16) unsigned short nodes_s[32][136];
  __shared__ __align__(16) u64 bits[128][17];
  __shared__ __align__(16) unsigned short vt_s[128][40];

  const int tid = threadIdx.x;
  const int lane = tid & 63;
  const int w = tid >> 6;
  const int q = lane >> 4;
  const int r = lane & 15;

  const int bid = blockIdx.x;
  const int c0 = (int)(((long long)bid * NCHUNK) >> 9);
  const int c1 = (int)(((long long)(bid + 1) * NCHUNK) >> 9);
  const int nch = c1 - c0;
  const int n0 = c0 * 32;

  {
    const int row0 = w * 16;
    int cb = 16 * lane;
    if (cb >= nch * 32) cb = 0;
    int4 cur[4], nxt[4];
    auto ldrow = [&](int rr, int4* dst) {
      const int* p = masks + (size_t)(row0 + rr) * NTOT + n0 + cb;
#pragma unroll
      for (int i = 0; i < 4; ++i) dst[i] = *(const int4*)(p + 4 * i);
    };
    ldrow(0, cur);
#pragma unroll 4
    for (int rr = 0; rr < 16; ++rr) {
      if (rr < 15) ldrow(rr + 1, nxt);
      const int* m = (const int*)cur;
      u32 b = 0;
#pragma unroll
      for (int e = 0; e < 16; ++e) b |= (u32)(m[e] != 0) << e;
      ((unsigned short*)bits)[(row0 + rr) * 68 + lane] = (unsigned short)b;
#pragma unroll
      for (int i = 0; i < 4; ++i) cur[i] = nxt[i];
    }
  }

  bf16x8 Wf[2][4];
  float btr, bgr;
  {
    const int d = w * 16 + r;
    btr = bt[d];
    bgr = bg[d];
#pragma unroll
    for (int ks = 0; ks < 4; ++ks) {
      u32 wv[4], gv[4];
#pragma unroll
      for (int j = 0; j < 4; ++j) {
        const int k = ks * 32 + q * 8 + 2 * j;
        wv[j] = f2bf2(Wt[k * 128 + d], Wt[(k + 1) * 128 + d]);
        gv[j] = f2bf2(Wg[k * 128 + d], Wg[(k + 1) * 128 + d]);
      }
      Wf[0][ks] = __builtin_bit_cast(bf16x8, *(ushort8*)wv);
      Wf[1][ks] = __builtin_bit_cast(bf16x8, *(ushort8*)gv);
    }
  }

  const f32x4 fzero = {0.f, 0.f, 0.f, 0.f};
  f32x4 acc[8];
#pragma unroll
  for (int i = 0; i < 8; ++i) acc[i] = fzero;

  float4 nf[2];
  auto issue = [&](int cloc) {
    const int k0 = n0 + cloc * 32;
#pragma unroll
    for (int it = 0; it < 2; ++it) {
      const int flat = it * 512 + tid;
      const int nrow = flat >> 5, nc4 = flat & 31;
      nf[it] = *(const float4*)(nodes + (size_t)(k0 + nrow) * 128 + nc4 * 4);
    }
  };

  issue(0);
  __syncthreads();

  const u32* bitw = (const u32*)bits;

  for (int c = 0; c < nch; ++c) {
    if (c) __syncthreads();
#pragma unroll
    for (int it = 0; it < 2; ++it) {
      const int flat = it * 512 + tid;
      const int nrow = flat >> 5, nc4 = flat & 31;
      const u32 lo = f2bf2(nf[it].x, nf[it].y);
      const u32 hi = f2bf2(nf[it].z, nf[it].w);
      *(u64*)&nodes_s[nrow][nc4 * 4] = (u64)lo | ((u64)hi << 32);
    }
    __syncthreads();
    if (c + 1 < nch) issue(c + 1);

    f32x4 aD[2], aG[2];
    aD[0] = fzero; aD[1] = fzero; aG[0] = fzero; aG[1] = fzero;
#pragma unroll
    for (int ks = 0; ks < 4; ++ks) {
      bf16x8 a0 = *(const bf16x8*)&nodes_s[r][ks * 32 + q * 8];
      bf16x8 a1 = *(const bf16x8*)&nodes_s[16 + r][ks * 32 + q * 8];
      aD[0] = __builtin_amdgcn_mfma_f32_16x16x32_bf16(a0, Wf[0][ks], aD[0], 0, 0, 0);
      aD[1] = __builtin_amdgcn_mfma_f32_16x16x32_bf16(a1, Wf[0][ks], aD[1], 0, 0, 0);
      aG[0] = __builtin_amdgcn_mfma_f32_16x16x32_bf16(a0, Wf[1][ks], aG[0], 0, 0, 0);
      aG[1] = __builtin_amdgcn_mfma_f32_16x16x32_bf16(a1, Wf[1][ks], aG[1], 0, 0, 0);
    }

    const int d = w * 16 + r;
#pragma unroll
    for (int mt = 0; mt < 2; ++mt) {
      float v[4];
#pragma unroll
      for (int reg = 0; reg < 4; ++reg) {
        const float x = aD[mt][reg] + btr;
        const float g = aG[mt][reg] + bgr;
        v[reg] = x * __builtin_amdgcn_rcpf(1.f + __expf(-g));
      }
      const u32 lo = f2bf2(v[0], v[1]);
      const u32 hi = f2bf2(v[2], v[3]);
      *(u64*)&vt_s[d][mt * 16 + q * 4] = (u64)lo | ((u64)hi << 32);
    }

    bf16x8 bfr = *(const bf16x8*)&vt_s[d][q * 8];
#pragma unroll
    for (int mt = 0; mt < 8; ++mt) {
      const u32 dw = bitw[(mt * 16 + r) * 34 + c];
      const u32 byte = (dw >> (q * 8)) & 0xffu;
      u32 p[4];
      p[0] = bits2bf2(byte, 0);
      p[1] = bits2bf2(byte, 2);
      p[2] = bits2bf2(byte, 4);
      p[3] = bits2bf2(byte, 6);
      bf16x8 a = __builtin_bit_cast(bf16x8, *(ushort8*)p);
      acc[mt] = __builtin_amdgcn_mfma_f32_16x16x32_bf16(a, bfr, acc[mt], 0, 0, 0);
    }
  }

#pragma unroll
  for (int mt = 0; mt < 8; ++mt)
#pragma unroll
    for (int reg = 0; reg < 4; ++reg) {
      const int b = mt * 16 + q * 4 + reg;
      const int d = w * 16 + r;
      atomicAdd(&outp[b * 128 + d], acc[mt][reg]);
    }
}

extern "C" void kernel_launch(void* const* d_in, const int* in_sizes, int n_in,
                              void* d_out, int out_size, void* d_ws, size_t ws_size,
                              hipStream_t stream) {
  const float* nodes = (const float*)d_in[0];
  const int*   masks = (const int*)d_in[1];
  const float* Wt    = (const float*)d_in[2];
  const float* bt    = (const float*)d_in[3];
  const float* Wg    = (const float*)d_in[4];
  const float* bg    = (const float*)d_in[5];
  float* out = (float*)d_out;

  (void)hipMemsetAsync(d_out, 0, (size_t)out_size * sizeof(float), stream);

  const size_t vt_bytes = (size_t)NCHUNK * 4096 * sizeof(unsigned short);  // 128 MB
  const size_t part_bytes = (size_t)NBLK2 * 16384 * sizeof(float);         // 33.5 MB

  if (ws_size >= vt_bytes + part_bytes) {
    unsigned short* vt = (unsigned short*)d_ws;
    float* part = (float*)((char*)d_ws + vt_bytes);
    agg_v<<<NBLK1, 512, 0, stream>>>(nodes, Wt, bt, Wg, bg, vt);
    agg_pool<false><<<NBLK2, 512, 0, stream>>>(masks, vt, part);
    agg_reduce<<<512, 256, 0, stream>>>(part, out);
  } else if (ws_size >= vt_bytes) {
    unsigned short* vt = (unsigned short*)d_ws;
    agg_v<<<NBLK1, 512, 0, stream>>>(nodes, Wt, bt, Wg, bg, vt);
    agg_pool<true><<<NBLK2, 512, 0, stream>>>(masks, vt, out);
  } else {
    agg_fused<<<512, 512, 0, stream>>>(nodes, masks, Wt, bt, Wg, bg, out);
  }
}